// Round 1
// baseline (274.380 us; speedup 1.0000x reference)
//
#include <hip/hip_runtime.h>

#define NTYPE 3
#define H 4
#define D 128
#define ALPHA 0.2f

typedef float f2 __attribute__((ext_vector_type(2)));
typedef float f4 __attribute__((ext_vector_type(4)));

// ---------------- Phase 1a: histogram of destination nodes ----------------
__global__ void count_kernel(const int* __restrict__ batch,
                             int* __restrict__ cnt, int E) {
    int r = blockIdx.x * blockDim.x + threadIdx.x;
    if (r >= E) return;
    const int* row = batch + 3 * r;
    int b0 = row[0], b1 = row[1], b2 = row[2];
    atomicAdd(&cnt[b0], 1);
    atomicAdd(&cnt[b1], 1);
    atomicAdd(&cnt[b2], 1);
}

// ---------------- Phase 1b: in-place exclusive scan (single block) ----------------
// 50k ints, one 1024-thread block; each thread owns a contiguous chunk.
__global__ void __launch_bounds__(1024) scan_kernel(int* __restrict__ cnt, int N) {
    __shared__ int lds[1024];
    const int tid = threadIdx.x;
    const int chunk = (N + 1023) >> 10;
    const int lo = tid * chunk;
    const int hi = min(lo + chunk, N);

    int s = 0;
    for (int i = lo; i < hi; ++i) s += cnt[i];
    lds[tid] = s;
    __syncthreads();
    for (int off = 1; off < 1024; off <<= 1) {
        int v = (tid >= off) ? lds[tid - off] : 0;
        __syncthreads();
        lds[tid] += v;
        __syncthreads();
    }
    int run = lds[tid] - s;   // exclusive prefix of this thread's chunk
    for (int i = lo; i < hi; ++i) {
        int c = cnt[i];
        cnt[i] = run;
        run += c;
    }
}

// ---------------- Phase 1c: scatter records into CSR slots ----------------
// cursor[] holds exclusive starts; after this kernel cursor[n] == end offset of
// node n (start of node n is cursor[n-1], or 0 for n==0).
// rec = {other_node_0, other_node_1, weight_row_index}
__global__ void scatter_kernel(const int* __restrict__ batch,
                               int* __restrict__ cursor,
                               int4* __restrict__ recs, int E) {
    int r = blockIdx.x * blockDim.x + threadIdx.x;
    if (r >= E) return;
    const int* row = batch + 3 * r;
    int b0 = row[0], b1 = row[1], b2 = row[2];
    // feat block i gathers columns != i in ascending order; weight row = i*E + r
    int s0 = atomicAdd(&cursor[b0], 1);
    recs[s0] = make_int4(b1, b2, r, 0);
    int s1 = atomicAdd(&cursor[b1], 1);
    recs[s1] = make_int4(b0, b2, E + r, 0);
    int s2 = atomicAdd(&cursor[b2], 1);
    recs[s2] = make_int4(b0, b1, 2 * E + r, 0);
}

// ---------------- Phase 2: per-node max-aggregate + residual + leaky ----------------
// One 64-thread block per node; each lane covers d = 2t, 2t+1 (float2 gathers).
// CSR range -> known trip count, address-independent rec loads, 2-way unroll.
__global__ void __launch_bounds__(64)
aggregate_kernel(const float* __restrict__ bfeat,
                 const float* __restrict__ attw,
                 const int4* __restrict__ recs,
                 const int* __restrict__ cursor,
                 float* __restrict__ out) {
    const int n = blockIdx.x;
    const int t = threadIdx.x;
    const int e = cursor[n];
    const int s = (n == 0) ? 0 : cursor[n - 1];

    const float NI = -__builtin_inff();
    f2 acc0 = {NI, NI}, acc1 = {NI, NI}, acc2 = {NI, NI}, acc3 = {NI, NI};

    int k = s;
    for (; k + 2 <= e; k += 2) {
        const int4 ra = recs[k];
        const int4 rb = recs[k + 1];
        const f2 fa0 = *(const f2*)(bfeat + (size_t)ra.x * D + 2 * t);
        const f2 fa1 = *(const f2*)(bfeat + (size_t)ra.y * D + 2 * t);
        const f2 fb0 = *(const f2*)(bfeat + (size_t)rb.x * D + 2 * t);
        const f2 fb1 = *(const f2*)(bfeat + (size_t)rb.y * D + 2 * t);
        const f4 wa0 = *(const f4*)(attw + (size_t)ra.z * 8);
        const f4 wa1 = *(const f4*)(attw + (size_t)ra.z * 8 + 4);
        const f4 wb0 = *(const f4*)(attw + (size_t)rb.z * 8);
        const f4 wb1 = *(const f4*)(attw + (size_t)rb.z * 8 + 4);

        acc0.x = fmaxf(acc0.x, fmaf(wa0.x, fa0.x, wa0.y * fa1.x));
        acc0.y = fmaxf(acc0.y, fmaf(wa0.x, fa0.y, wa0.y * fa1.y));
        acc1.x = fmaxf(acc1.x, fmaf(wa0.z, fa0.x, wa0.w * fa1.x));
        acc1.y = fmaxf(acc1.y, fmaf(wa0.z, fa0.y, wa0.w * fa1.y));
        acc2.x = fmaxf(acc2.x, fmaf(wa1.x, fa0.x, wa1.y * fa1.x));
        acc2.y = fmaxf(acc2.y, fmaf(wa1.x, fa0.y, wa1.y * fa1.y));
        acc3.x = fmaxf(acc3.x, fmaf(wa1.z, fa0.x, wa1.w * fa1.x));
        acc3.y = fmaxf(acc3.y, fmaf(wa1.z, fa0.y, wa1.w * fa1.y));

        acc0.x = fmaxf(acc0.x, fmaf(wb0.x, fb0.x, wb0.y * fb1.x));
        acc0.y = fmaxf(acc0.y, fmaf(wb0.x, fb0.y, wb0.y * fb1.y));
        acc1.x = fmaxf(acc1.x, fmaf(wb0.z, fb0.x, wb0.w * fb1.x));
        acc1.y = fmaxf(acc1.y, fmaf(wb0.z, fb0.y, wb0.w * fb1.y));
        acc2.x = fmaxf(acc2.x, fmaf(wb1.x, fb0.x, wb1.y * fb1.x));
        acc2.y = fmaxf(acc2.y, fmaf(wb1.x, fb0.y, wb1.y * fb1.y));
        acc3.x = fmaxf(acc3.x, fmaf(wb1.z, fb0.x, wb1.w * fb1.x));
        acc3.y = fmaxf(acc3.y, fmaf(wb1.z, fb0.y, wb1.w * fb1.y));
    }
    if (k < e) {
        const int4 ra = recs[k];
        const f2 fa0 = *(const f2*)(bfeat + (size_t)ra.x * D + 2 * t);
        const f2 fa1 = *(const f2*)(bfeat + (size_t)ra.y * D + 2 * t);
        const f4 wa0 = *(const f4*)(attw + (size_t)ra.z * 8);
        const f4 wa1 = *(const f4*)(attw + (size_t)ra.z * 8 + 4);
        acc0.x = fmaxf(acc0.x, fmaf(wa0.x, fa0.x, wa0.y * fa1.x));
        acc0.y = fmaxf(acc0.y, fmaf(wa0.x, fa0.y, wa0.y * fa1.y));
        acc1.x = fmaxf(acc1.x, fmaf(wa0.z, fa0.x, wa0.w * fa1.x));
        acc1.y = fmaxf(acc1.y, fmaf(wa0.z, fa0.y, wa0.w * fa1.y));
        acc2.x = fmaxf(acc2.x, fmaf(wa1.x, fa0.x, wa1.y * fa1.x));
        acc2.y = fmaxf(acc2.y, fmaf(wa1.x, fa0.y, wa1.y * fa1.y));
        acc3.x = fmaxf(acc3.x, fmaf(wa1.z, fa0.x, wa1.w * fa1.x));
        acc3.y = fmaxf(acc3.y, fmaf(wa1.z, fa0.y, wa1.w * fa1.y));
    }

    const f2 br = *(const f2*)(bfeat + (size_t)n * D + 2 * t);
    float* o = out + (size_t)n * (H * D) + 2 * t;
    f2 v;

    v.x = br.x + acc0.x; v.y = br.y + acc0.y;
    v.x = v.x > 0.f ? v.x : ALPHA * v.x; v.y = v.y > 0.f ? v.y : ALPHA * v.y;
    __builtin_nontemporal_store(v, (f2*)(o + 0 * D));

    v.x = br.x + acc1.x; v.y = br.y + acc1.y;
    v.x = v.x > 0.f ? v.x : ALPHA * v.x; v.y = v.y > 0.f ? v.y : ALPHA * v.y;
    __builtin_nontemporal_store(v, (f2*)(o + 1 * D));

    v.x = br.x + acc2.x; v.y = br.y + acc2.y;
    v.x = v.x > 0.f ? v.x : ALPHA * v.x; v.y = v.y > 0.f ? v.y : ALPHA * v.y;
    __builtin_nontemporal_store(v, (f2*)(o + 2 * D));

    v.x = br.x + acc3.x; v.y = br.y + acc3.y;
    v.x = v.x > 0.f ? v.x : ALPHA * v.x; v.y = v.y > 0.f ? v.y : ALPHA * v.y;
    __builtin_nontemporal_store(v, (f2*)(o + 3 * D));
}

extern "C" void kernel_launch(void* const* d_in, const int* in_sizes, int n_in,
                              void* d_out, int out_size, void* d_ws, size_t ws_size,
                              hipStream_t stream) {
    const int* batch   = (const int*)d_in[0];
    const float* bfeat = (const float*)d_in[1];
    const float* attw  = (const float*)d_in[2];
    const int E = in_sizes[0] / NTYPE;
    const int N = in_sizes[1] / D;

    // workspace: cursor (N ints) | recs (M int4), recs offset rounded to 16 B.
    int* cursor = (int*)d_ws;
    size_t rec_off = (((size_t)N * sizeof(int)) + 15) & ~(size_t)15;
    int4* recs = (int4*)((char*)d_ws + rec_off);

    hipMemsetAsync(cursor, 0, sizeof(int) * (size_t)N, stream);
    count_kernel<<<(E + 255) / 256, 256, 0, stream>>>(batch, cursor, E);
    scan_kernel<<<1, 1024, 0, stream>>>(cursor, N);
    scatter_kernel<<<(E + 255) / 256, 256, 0, stream>>>(batch, cursor, recs, E);
    aggregate_kernel<<<N, 64, 0, stream>>>(bfeat, attw, recs, cursor, (float*)d_out);
}

// Round 2
// 203.897 us; speedup vs baseline: 1.3457x; 1.3457x over previous
//
#include <hip/hip_runtime.h>

#define NTYPE 3
#define H 4
#define D 128
#define ALPHA 0.2f

#define SCAN_TILE 1024   // elements per scan block (256 thr x int4)

typedef float f2 __attribute__((ext_vector_type(2)));
typedef float f4 __attribute__((ext_vector_type(4)));

// ---------------- Phase 1a: histogram of destination nodes ----------------
__global__ void count_kernel(const int* __restrict__ batch,
                             int* __restrict__ cnt, int E) {
    int r = blockIdx.x * blockDim.x + threadIdx.x;
    if (r >= E) return;
    const int* row = batch + 3 * r;
    atomicAdd(&cnt[row[0]], 1);
    atomicAdd(&cnt[row[1]], 1);
    atomicAdd(&cnt[row[2]], 1);
}

// ---------------- Phase 1b-i: per-block exclusive scan (in-place) ----------------
// 49 blocks x 1024 elements. Block total -> bsum[blockIdx] (stashed in recs head,
// which is not written until scatter_kernel).
__global__ void __launch_bounds__(256)
bscan_kernel(int* __restrict__ cnt, int* __restrict__ bsum, int N) {
    __shared__ int lds[256];
    const int tid = threadIdx.x;
    const int base = blockIdx.x * SCAN_TILE + tid * 4;

    int4 v = make_int4(0, 0, 0, 0);
    if (base + 3 < N) v = *(const int4*)(cnt + base);
    else {
        if (base + 0 < N) v.x = cnt[base + 0];
        if (base + 1 < N) v.y = cnt[base + 1];
        if (base + 2 < N) v.z = cnt[base + 2];
        if (base + 3 < N) v.w = cnt[base + 3];
    }
    const int s = v.x + v.y + v.z + v.w;

    lds[tid] = s;
    __syncthreads();
    for (int off = 1; off < 256; off <<= 1) {
        int t = (tid >= off) ? lds[tid - off] : 0;
        __syncthreads();
        lds[tid] += t;
        __syncthreads();
    }
    const int excl = lds[tid] - s;
    if (tid == 255) bsum[blockIdx.x] = lds[255];

    int4 o;
    o.x = excl;
    o.y = excl + v.x;
    o.z = excl + v.x + v.y;
    o.w = excl + v.x + v.y + v.z;
    if (base + 3 < N) *(int4*)(cnt + base) = o;
    else {
        if (base + 0 < N) cnt[base + 0] = o.x;
        if (base + 1 < N) cnt[base + 1] = o.y;
        if (base + 2 < N) cnt[base + 2] = o.z;
        if (base + 3 < N) cnt[base + 3] = o.w;
    }
}

// ---------------- Phase 1b-ii: add block-sum prefix to each tile ----------------
// Each block recomputes its offset from the <=64 block sums ahead of it
// (L2-resident) -- fuses the sums-scan pass into the add pass.
__global__ void __launch_bounds__(256)
add_kernel(int* __restrict__ cnt, const int* __restrict__ bsum, int N) {
    __shared__ int off_s;
    const int tid = threadIdx.x;
    if (tid < 64) {
        int acc = 0;
        for (int i = tid; i < (int)blockIdx.x; i += 64) acc += bsum[i];
        for (int o = 32; o > 0; o >>= 1) acc += __shfl_down(acc, o);
        if (tid == 0) off_s = acc;
    }
    __syncthreads();
    const int off = off_s;

    const int base = blockIdx.x * SCAN_TILE + tid * 4;
    if (base + 3 < N) {
        int4 v = *(int4*)(cnt + base);
        v.x += off; v.y += off; v.z += off; v.w += off;
        *(int4*)(cnt + base) = v;
    } else {
        for (int i = 0; i < 4; ++i)
            if (base + i < N) cnt[base + i] += off;
    }
}

// ---------------- Phase 1c: scatter records into CSR slots ----------------
// cursor[] holds exclusive starts; after this kernel cursor[n] == end offset of
// node n (start of node n is cursor[n-1], or 0 for n==0).
// rec = {other_node_0, other_node_1, weight_row_index}
__global__ void scatter_kernel(const int* __restrict__ batch,
                               int* __restrict__ cursor,
                               int4* __restrict__ recs, int E) {
    int r = blockIdx.x * blockDim.x + threadIdx.x;
    if (r >= E) return;
    const int* row = batch + 3 * r;
    int b0 = row[0], b1 = row[1], b2 = row[2];
    // feat block i gathers columns != i in ascending order; weight row = i*E + r
    int s0 = atomicAdd(&cursor[b0], 1);
    recs[s0] = make_int4(b1, b2, r, 0);
    int s1 = atomicAdd(&cursor[b1], 1);
    recs[s1] = make_int4(b0, b2, E + r, 0);
    int s2 = atomicAdd(&cursor[b2], 1);
    recs[s2] = make_int4(b0, b1, 2 * E + r, 0);
}

// ---------------- Phase 2: per-node max-aggregate + residual + leaky ----------------
// One 64-thread block per node; each lane covers d = 2t, 2t+1 (float2 gathers).
// CSR range -> known trip count, address-independent rec loads, 2-way unroll.
__global__ void __launch_bounds__(64)
aggregate_kernel(const float* __restrict__ bfeat,
                 const float* __restrict__ attw,
                 const int4* __restrict__ recs,
                 const int* __restrict__ cursor,
                 float* __restrict__ out) {
    const int n = blockIdx.x;
    const int t = threadIdx.x;
    const int e = cursor[n];
    const int s = (n == 0) ? 0 : cursor[n - 1];

    const float NI = -__builtin_inff();
    f2 acc0 = {NI, NI}, acc1 = {NI, NI}, acc2 = {NI, NI}, acc3 = {NI, NI};

    int k = s;
    for (; k + 2 <= e; k += 2) {
        const int4 ra = recs[k];
        const int4 rb = recs[k + 1];
        const f2 fa0 = *(const f2*)(bfeat + (size_t)ra.x * D + 2 * t);
        const f2 fa1 = *(const f2*)(bfeat + (size_t)ra.y * D + 2 * t);
        const f2 fb0 = *(const f2*)(bfeat + (size_t)rb.x * D + 2 * t);
        const f2 fb1 = *(const f2*)(bfeat + (size_t)rb.y * D + 2 * t);
        const f4 wa0 = *(const f4*)(attw + (size_t)ra.z * 8);
        const f4 wa1 = *(const f4*)(attw + (size_t)ra.z * 8 + 4);
        const f4 wb0 = *(const f4*)(attw + (size_t)rb.z * 8);
        const f4 wb1 = *(const f4*)(attw + (size_t)rb.z * 8 + 4);

        acc0.x = fmaxf(acc0.x, fmaf(wa0.x, fa0.x, wa0.y * fa1.x));
        acc0.y = fmaxf(acc0.y, fmaf(wa0.x, fa0.y, wa0.y * fa1.y));
        acc1.x = fmaxf(acc1.x, fmaf(wa0.z, fa0.x, wa0.w * fa1.x));
        acc1.y = fmaxf(acc1.y, fmaf(wa0.z, fa0.y, wa0.w * fa1.y));
        acc2.x = fmaxf(acc2.x, fmaf(wa1.x, fa0.x, wa1.y * fa1.x));
        acc2.y = fmaxf(acc2.y, fmaf(wa1.x, fa0.y, wa1.y * fa1.y));
        acc3.x = fmaxf(acc3.x, fmaf(wa1.z, fa0.x, wa1.w * fa1.x));
        acc3.y = fmaxf(acc3.y, fmaf(wa1.z, fa0.y, wa1.w * fa1.y));

        acc0.x = fmaxf(acc0.x, fmaf(wb0.x, fb0.x, wb0.y * fb1.x));
        acc0.y = fmaxf(acc0.y, fmaf(wb0.x, fb0.y, wb0.y * fb1.y));
        acc1.x = fmaxf(acc1.x, fmaf(wb0.z, fb0.x, wb0.w * fb1.x));
        acc1.y = fmaxf(acc1.y, fmaf(wb0.z, fb0.y, wb0.w * fb1.y));
        acc2.x = fmaxf(acc2.x, fmaf(wb1.x, fb0.x, wb1.y * fb1.x));
        acc2.y = fmaxf(acc2.y, fmaf(wb1.x, fb0.y, wb1.y * fb1.y));
        acc3.x = fmaxf(acc3.x, fmaf(wb1.z, fb0.x, wb1.w * fb1.x));
        acc3.y = fmaxf(acc3.y, fmaf(wb1.z, fb0.y, wb1.w * fb1.y));
    }
    if (k < e) {
        const int4 ra = recs[k];
        const f2 fa0 = *(const f2*)(bfeat + (size_t)ra.x * D + 2 * t);
        const f2 fa1 = *(const f2*)(bfeat + (size_t)ra.y * D + 2 * t);
        const f4 wa0 = *(const f4*)(attw + (size_t)ra.z * 8);
        const f4 wa1 = *(const f4*)(attw + (size_t)ra.z * 8 + 4);
        acc0.x = fmaxf(acc0.x, fmaf(wa0.x, fa0.x, wa0.y * fa1.x));
        acc0.y = fmaxf(acc0.y, fmaf(wa0.x, fa0.y, wa0.y * fa1.y));
        acc1.x = fmaxf(acc1.x, fmaf(wa0.z, fa0.x, wa0.w * fa1.x));
        acc1.y = fmaxf(acc1.y, fmaf(wa0.z, fa0.y, wa0.w * fa1.y));
        acc2.x = fmaxf(acc2.x, fmaf(wa1.x, fa0.x, wa1.y * fa1.x));
        acc2.y = fmaxf(acc2.y, fmaf(wa1.x, fa0.y, wa1.y * fa1.y));
        acc3.x = fmaxf(acc3.x, fmaf(wa1.z, fa0.x, wa1.w * fa1.x));
        acc3.y = fmaxf(acc3.y, fmaf(wa1.z, fa0.y, wa1.w * fa1.y));
    }

    const f2 br = *(const f2*)(bfeat + (size_t)n * D + 2 * t);
    float* o = out + (size_t)n * (H * D) + 2 * t;
    f2 v;

    v.x = br.x + acc0.x; v.y = br.y + acc0.y;
    v.x = v.x > 0.f ? v.x : ALPHA * v.x; v.y = v.y > 0.f ? v.y : ALPHA * v.y;
    __builtin_nontemporal_store(v, (f2*)(o + 0 * D));

    v.x = br.x + acc1.x; v.y = br.y + acc1.y;
    v.x = v.x > 0.f ? v.x : ALPHA * v.x; v.y = v.y > 0.f ? v.y : ALPHA * v.y;
    __builtin_nontemporal_store(v, (f2*)(o + 1 * D));

    v.x = br.x + acc2.x; v.y = br.y + acc2.y;
    v.x = v.x > 0.f ? v.x : ALPHA * v.x; v.y = v.y > 0.f ? v.y : ALPHA * v.y;
    __builtin_nontemporal_store(v, (f2*)(o + 2 * D));

    v.x = br.x + acc3.x; v.y = br.y + acc3.y;
    v.x = v.x > 0.f ? v.x : ALPHA * v.x; v.y = v.y > 0.f ? v.y : ALPHA * v.y;
    __builtin_nontemporal_store(v, (f2*)(o + 3 * D));
}

extern "C" void kernel_launch(void* const* d_in, const int* in_sizes, int n_in,
                              void* d_out, int out_size, void* d_ws, size_t ws_size,
                              hipStream_t stream) {
    const int* batch   = (const int*)d_in[0];
    const float* bfeat = (const float*)d_in[1];
    const float* attw  = (const float*)d_in[2];
    const int E = in_sizes[0] / NTYPE;
    const int N = in_sizes[1] / D;

    // workspace: cursor (N ints) | recs (M int4), recs offset rounded to 16 B.
    // Block sums for the scan live in the head of recs (overwritten later by
    // scatter) -> zero extra workspace.
    int* cursor = (int*)d_ws;
    size_t rec_off = (((size_t)N * sizeof(int)) + 15) & ~(size_t)15;
    int4* recs = (int4*)((char*)d_ws + rec_off);
    int* bsum = (int*)recs;

    const int nb = (N + SCAN_TILE - 1) / SCAN_TILE;

    hipMemsetAsync(cursor, 0, sizeof(int) * (size_t)N, stream);
    count_kernel<<<(E + 255) / 256, 256, 0, stream>>>(batch, cursor, E);
    bscan_kernel<<<nb, 256, 0, stream>>>(cursor, bsum, N);
    add_kernel<<<nb, 256, 0, stream>>>(cursor, bsum, N);
    scatter_kernel<<<(E + 255) / 256, 256, 0, stream>>>(batch, cursor, recs, E);
    aggregate_kernel<<<N, 64, 0, stream>>>(bfeat, attw, recs, cursor, (float*)d_out);
}

// Round 4
// 196.425 us; speedup vs baseline: 1.3969x; 1.0380x over previous
//
#include <hip/hip_runtime.h>

#define NTYPE 3
#define H 4
#define D 128
#define ALPHA 0.2f

#define SCAN_TILE 1024   // elements per scan block (256 thr x int4)

typedef float f2 __attribute__((ext_vector_type(2)));
typedef float f4 __attribute__((ext_vector_type(4)));

// ---------------- Phase 1a: histogram + rank capture ----------------
// The atomicAdd return value IS the within-node rank; store it so the scatter
// needs no atomics. rnk lives in the head of d_out (dead until aggregate).
__global__ void count_kernel(const int* __restrict__ batch,
                             int* __restrict__ cnt,
                             int* __restrict__ rnk, int E) {
    int r = blockIdx.x * blockDim.x + threadIdx.x;
    if (r >= E) return;
    const int* row = batch + 3 * r;
    int b0 = row[0], b1 = row[1], b2 = row[2];
    rnk[r]         = atomicAdd(&cnt[b0], 1);
    rnk[E + r]     = atomicAdd(&cnt[b1], 1);
    rnk[2 * E + r] = atomicAdd(&cnt[b2], 1);
}

// ---------------- Phase 1b-i: per-block exclusive scan (in-place) ----------------
// 49 blocks x 1024 elements. Block total -> bsum[blockIdx] (stashed in recs head,
// which is not written until scatter_kernel).
__global__ void __launch_bounds__(256)
bscan_kernel(int* __restrict__ cnt, int* __restrict__ bsum, int N) {
    __shared__ int lds[256];
    const int tid = threadIdx.x;
    const int base = blockIdx.x * SCAN_TILE + tid * 4;

    int4 v = make_int4(0, 0, 0, 0);
    if (base + 3 < N) v = *(const int4*)(cnt + base);
    else {
        if (base + 0 < N) v.x = cnt[base + 0];
        if (base + 1 < N) v.y = cnt[base + 1];
        if (base + 2 < N) v.z = cnt[base + 2];
        if (base + 3 < N) v.w = cnt[base + 3];
    }
    const int s = v.x + v.y + v.z + v.w;

    lds[tid] = s;
    __syncthreads();
    for (int off = 1; off < 256; off <<= 1) {
        int t = (tid >= off) ? lds[tid - off] : 0;
        __syncthreads();
        lds[tid] += t;
        __syncthreads();
    }
    const int excl = lds[tid] - s;
    if (tid == 255) bsum[blockIdx.x] = lds[255];

    int4 o;
    o.x = excl;
    o.y = excl + v.x;
    o.z = excl + v.x + v.y;
    o.w = excl + v.x + v.y + v.z;
    if (base + 3 < N) *(int4*)(cnt + base) = o;
    else {
        if (base + 0 < N) cnt[base + 0] = o.x;
        if (base + 1 < N) cnt[base + 1] = o.y;
        if (base + 2 < N) cnt[base + 2] = o.z;
        if (base + 3 < N) cnt[base + 3] = o.w;
    }
}

// ---------------- Phase 1b-ii: add block-sum prefix to each tile ----------------
__global__ void __launch_bounds__(256)
add_kernel(int* __restrict__ cnt, const int* __restrict__ bsum, int N) {
    __shared__ int off_s;
    const int tid = threadIdx.x;
    if (tid < 64) {
        int acc = 0;
        for (int i = tid; i < (int)blockIdx.x; i += 64) acc += bsum[i];
        for (int o = 32; o > 0; o >>= 1) acc += __shfl_down(acc, o);
        if (tid == 0) off_s = acc;
    }
    __syncthreads();
    const int off = off_s;

    const int base = blockIdx.x * SCAN_TILE + tid * 4;
    if (base + 3 < N) {
        int4 v = *(int4*)(cnt + base);
        v.x += off; v.y += off; v.z += off; v.w += off;
        *(int4*)(cnt + base) = v;
    } else {
        for (int i = 0; i < 4; ++i)
            if (base + i < N) cnt[base + i] += off;
    }
}

// ---------------- Phase 1c: atomic-free scatter into CSR slots ----------------
// slot = start[dest] + rank. cursor[] holds exclusive starts and is NOT mutated.
// rec = {other_node_0, other_node_1, weight_row_index}
__global__ void scatter_kernel(const int* __restrict__ batch,
                               const int* __restrict__ start,
                               const int* __restrict__ rnk,
                               int4* __restrict__ recs, int E) {
    int r = blockIdx.x * blockDim.x + threadIdx.x;
    if (r >= E) return;
    const int* row = batch + 3 * r;
    int b0 = row[0], b1 = row[1], b2 = row[2];
    int s0 = start[b0] + rnk[r];
    int s1 = start[b1] + rnk[E + r];
    int s2 = start[b2] + rnk[2 * E + r];
    recs[s0] = make_int4(b1, b2, r, 0);
    recs[s1] = make_int4(b0, b2, E + r, 0);
    recs[s2] = make_int4(b0, b1, 2 * E + r, 0);
}

// ---------------- Phase 2: per-node max-aggregate + residual + leaky ----------------
// One 64-thread block per node; each lane covers d = 2t, 2t+1 (float2 gathers).
// CSR range [cursor[n], cursor[n+1]) -> known trip count, independent rec loads.
__global__ void __launch_bounds__(64)
aggregate_kernel(const float* __restrict__ bfeat,
                 const float* __restrict__ attw,
                 const int4* __restrict__ recs,
                 const int* __restrict__ cursor,
                 float* __restrict__ out, int M) {
    const int n = blockIdx.x;
    const int t = threadIdx.x;
    const int s = cursor[n];
    const int e = (n == (int)gridDim.x - 1) ? M : cursor[n + 1];

    const float NI = -__builtin_inff();
    f2 acc0 = {NI, NI}, acc1 = {NI, NI}, acc2 = {NI, NI}, acc3 = {NI, NI};

    int k = s;
    for (; k + 2 <= e; k += 2) {
        const int4 ra = recs[k];
        const int4 rb = recs[k + 1];
        const f2 fa0 = *(const f2*)(bfeat + (size_t)ra.x * D + 2 * t);
        const f2 fa1 = *(const f2*)(bfeat + (size_t)ra.y * D + 2 * t);
        const f2 fb0 = *(const f2*)(bfeat + (size_t)rb.x * D + 2 * t);
        const f2 fb1 = *(const f2*)(bfeat + (size_t)rb.y * D + 2 * t);
        const f4 wa0 = *(const f4*)(attw + (size_t)ra.z * 8);
        const f4 wa1 = *(const f4*)(attw + (size_t)ra.z * 8 + 4);
        const f4 wb0 = *(const f4*)(attw + (size_t)rb.z * 8);
        const f4 wb1 = *(const f4*)(attw + (size_t)rb.z * 8 + 4);

        acc0.x = fmaxf(acc0.x, fmaf(wa0.x, fa0.x, wa0.y * fa1.x));
        acc0.y = fmaxf(acc0.y, fmaf(wa0.x, fa0.y, wa0.y * fa1.y));
        acc1.x = fmaxf(acc1.x, fmaf(wa0.z, fa0.x, wa0.w * fa1.x));
        acc1.y = fmaxf(acc1.y, fmaf(wa0.z, fa0.y, wa0.w * fa1.y));
        acc2.x = fmaxf(acc2.x, fmaf(wa1.x, fa0.x, wa1.y * fa1.x));
        acc2.y = fmaxf(acc2.y, fmaf(wa1.x, fa0.y, wa1.y * fa1.y));
        acc3.x = fmaxf(acc3.x, fmaf(wa1.z, fa0.x, wa1.w * fa1.x));
        acc3.y = fmaxf(acc3.y, fmaf(wa1.z, fa0.y, wa1.w * fa1.y));

        acc0.x = fmaxf(acc0.x, fmaf(wb0.x, fb0.x, wb0.y * fb1.x));
        acc0.y = fmaxf(acc0.y, fmaf(wb0.x, fb0.y, wb0.y * fb1.y));
        acc1.x = fmaxf(acc1.x, fmaf(wb0.z, fb0.x, wb0.w * fb1.x));
        acc1.y = fmaxf(acc1.y, fmaf(wb0.z, fb0.y, wb0.w * fb1.y));
        acc2.x = fmaxf(acc2.x, fmaf(wb1.x, fb0.x, wb1.y * fb1.x));
        acc2.y = fmaxf(acc2.y, fmaf(wb1.x, fb0.y, wb1.y * fb1.y));
        acc3.x = fmaxf(acc3.x, fmaf(wb1.z, fb0.x, wb1.w * fb1.x));
        acc3.y = fmaxf(acc3.y, fmaf(wb1.z, fb0.y, wb1.w * fb1.y));
    }
    if (k < e) {
        const int4 ra = recs[k];
        const f2 fa0 = *(const f2*)(bfeat + (size_t)ra.x * D + 2 * t);
        const f2 fa1 = *(const f2*)(bfeat + (size_t)ra.y * D + 2 * t);
        const f4 wa0 = *(const f4*)(attw + (size_t)ra.z * 8);
        const f4 wa1 = *(const f4*)(attw + (size_t)ra.z * 8 + 4);
        acc0.x = fmaxf(acc0.x, fmaf(wa0.x, fa0.x, wa0.y * fa1.x));
        acc0.y = fmaxf(acc0.y, fmaf(wa0.x, fa0.y, wa0.y * fa1.y));
        acc1.x = fmaxf(acc1.x, fmaf(wa0.z, fa0.x, wa0.w * fa1.x));
        acc1.y = fmaxf(acc1.y, fmaf(wa0.z, fa0.y, wa0.w * fa1.y));
        acc2.x = fmaxf(acc2.x, fmaf(wa1.x, fa0.x, wa1.y * fa1.x));
        acc2.y = fmaxf(acc2.y, fmaf(wa1.x, fa0.y, wa1.y * fa1.y));
        acc3.x = fmaxf(acc3.x, fmaf(wa1.z, fa0.x, wa1.w * fa1.x));
        acc3.y = fmaxf(acc3.y, fmaf(wa1.z, fa0.y, wa1.w * fa1.y));
    }

    const f2 br = *(const f2*)(bfeat + (size_t)n * D + 2 * t);
    float* o = out + (size_t)n * (H * D) + 2 * t;
    f2 v;

    v.x = br.x + acc0.x; v.y = br.y + acc0.y;
    v.x = v.x > 0.f ? v.x : ALPHA * v.x; v.y = v.y > 0.f ? v.y : ALPHA * v.y;
    __builtin_nontemporal_store(v, (f2*)(o + 0 * D));

    v.x = br.x + acc1.x; v.y = br.y + acc1.y;
    v.x = v.x > 0.f ? v.x : ALPHA * v.x; v.y = v.y > 0.f ? v.y : ALPHA * v.y;
    __builtin_nontemporal_store(v, (f2*)(o + 1 * D));

    v.x = br.x + acc2.x; v.y = br.y + acc2.y;
    v.x = v.x > 0.f ? v.x : ALPHA * v.x; v.y = v.y > 0.f ? v.y : ALPHA * v.y;
    __builtin_nontemporal_store(v, (f2*)(o + 2 * D));

    v.x = br.x + acc3.x; v.y = br.y + acc3.y;
    v.x = v.x > 0.f ? v.x : ALPHA * v.x; v.y = v.y > 0.f ? v.y : ALPHA * v.y;
    __builtin_nontemporal_store(v, (f2*)(o + 3 * D));
}

extern "C" void kernel_launch(void* const* d_in, const int* in_sizes, int n_in,
                              void* d_out, int out_size, void* d_ws, size_t ws_size,
                              hipStream_t stream) {
    const int* batch   = (const int*)d_in[0];
    const float* bfeat = (const float*)d_in[1];
    const float* attw  = (const float*)d_in[2];
    const int E = in_sizes[0] / NTYPE;
    const int N = in_sizes[1] / D;
    const int M = NTYPE * E;

    // workspace: cursor (N ints) | recs (M int4), recs offset rounded to 16 B.
    // Scan block sums live in the head of recs (overwritten later by scatter).
    // Ranks (3E ints) live in the head of d_out (dead until aggregate writes it).
    int* cursor = (int*)d_ws;
    size_t rec_off = (((size_t)N * sizeof(int)) + 15) & ~(size_t)15;
    int4* recs = (int4*)((char*)d_ws + rec_off);
    int* bsum = (int*)recs;
    int* rnk  = (int*)d_out;

    const int nb = (N + SCAN_TILE - 1) / SCAN_TILE;

    hipMemsetAsync(cursor, 0, sizeof(int) * (size_t)N, stream);
    count_kernel<<<(E + 255) / 256, 256, 0, stream>>>(batch, cursor, rnk, E);
    bscan_kernel<<<nb, 256, 0, stream>>>(cursor, bsum, N);
    add_kernel<<<nb, 256, 0, stream>>>(cursor, bsum, N);
    scatter_kernel<<<(E + 255) / 256, 256, 0, stream>>>(batch, cursor, rnk, recs, E);
    aggregate_kernel<<<N, 64, 0, stream>>>(bfeat, attw, recs, cursor, (float*)d_out, M);
}